// Round 5
// baseline (42.735 us; speedup 1.0000x reference)
//
#include <hip/hip_runtime.h>
#include <hip/hip_bf16.h>

#define EPS 1e-5f

typedef float floatx4 __attribute__((ext_vector_type(4)));

// Fully fused: slice + LayerNorm + dot(W) + bias + sigmoid, single pass.
// logit = rs*(sum(x*gw) - mu*sum(gw)) + sum(beta*W) + bias,  gw = gamma*W
//
// Barrier-free / LDS-free variant: each 16-lane group holds the ENTIRE
// gw[768] in registers (16 lanes x 12 float4 = 768 floats; idx = sl*4+k*64
// covers 0..767). The per-wave prologue computes gw and both scalar consts
// using only intra-group shuffles (xor masks <=8 stay inside the group),
// so there is no LDS traffic and no __syncthreads anywhere.
// x is streamed once -> nontemporal loads keep it out of the caches.
__global__ __launch_bounds__(256) void head_kernel(
    const float* __restrict__ x, const float* __restrict__ gamma,
    const float* __restrict__ beta, const float* __restrict__ W,
    const float* __restrict__ bias, float* __restrict__ out) {
    const int t    = threadIdx.x;
    const int lane = t & 63;
    const int wv   = t >> 6;
    const int sl   = lane & 15;   // sub-lane within the row's 16-lane group
    const int grp  = lane >> 4;   // which of the wave's 4 rows

    // ---- prologue: gw into registers, consts via intra-group reduce ----
    floatx4 gw[12];
    float sgw = 0.f, sbw = 0.f;
#pragma unroll
    for (int k = 0; k < 12; ++k) {
        const int idx = sl * 4 + k * 64;
        floatx4 w  = *reinterpret_cast<const floatx4*>(W + idx);
        floatx4 g  = *reinterpret_cast<const floatx4*>(gamma + idx);
        floatx4 bt = *reinterpret_cast<const floatx4*>(beta + idx);
        floatx4 gv = g * w;
        gw[k] = gv;
        sgw += gv.x + gv.y + gv.z + gv.w;
        sbw += bt.x * w.x + bt.y * w.y + bt.z * w.z + bt.w * w.w;
    }
#pragma unroll
    for (int m = 8; m; m >>= 1) {
        sgw += __shfl_xor(sgw, m);
        sbw += __shfl_xor(sbw, m);
    }
    const float c0 = sgw;
    const float c1 = sbw + bias[0];
    const float inv_e = 1.0f / 768.0f;

    // ---- main: 16 rows/block = 4 waves x 4 rows; 16 lanes per row ----
    const int row = blockIdx.x * 16 + wv * 4 + grp;   // 0 .. 65535
    const int b   = row >> 8;
    const int n   = row & 255;
    const float* __restrict__ xr = x + (size_t)(b * 257 + n + 1) * 768;

    float s1 = 0.f, s2 = 0.f, s3 = 0.f;
#pragma unroll
    for (int k = 0; k < 12; ++k) {
        const int idx = sl * 4 + k * 64;  // 16 lanes x float4 = 256B/group
        floatx4 v = __builtin_nontemporal_load(
            reinterpret_cast<const floatx4*>(xr + idx));
        s1 += v.x + v.y + v.z + v.w;
        s2 += v.x * v.x + v.y * v.y + v.z * v.z + v.w * v.w;
        s3 += v.x * gw[k].x + v.y * gw[k].y + v.z * gw[k].z + v.w * gw[k].w;
    }
    // butterfly over the 16-lane group: reduces the wave's 4 rows at once
#pragma unroll
    for (int m = 8; m; m >>= 1) {
        s1 += __shfl_xor(s1, m);
        s2 += __shfl_xor(s2, m);
        s3 += __shfl_xor(s3, m);
    }
    if (sl == 0) {
        float mu  = s1 * inv_e;
        float var = s2 * inv_e - mu * mu;
        float rs  = rsqrtf(var + EPS);
        float logit = rs * (s3 - mu * c0) + c1;
        out[row] = 1.0f / (1.0f + __expf(-logit));  // lanes 0/16/32/48 -> 16B
    }
}

extern "C" void kernel_launch(void* const* d_in, const int* in_sizes, int n_in,
                              void* d_out, int out_size, void* d_ws, size_t ws_size,
                              hipStream_t stream) {
    const float* x     = (const float*)d_in[0];   // (256, 257, 768)
    const float* gamma = (const float*)d_in[1];   // (768,)
    const float* beta  = (const float*)d_in[2];   // (768,)
    const float* W     = (const float*)d_in[3];   // (1, 768)
    const float* bias  = (const float*)d_in[4];   // (1,)
    float* out = (float*)d_out;                   // 65536 floats

    const int rows = 256 * 256;                   // 16 rows per block
    head_kernel<<<rows / 16, 256, 0, stream>>>(x, gamma, beta, W, bias, out);
}

// Round 6
// 36.322 us; speedup vs baseline: 1.1766x; 1.1766x over previous
//
#include <hip/hip_runtime.h>
#include <hip/hip_bf16.h>

#define EPS 1e-5f

typedef float floatx4 __attribute__((ext_vector_type(4)));

// Fully fused: slice + LayerNorm + dot(W) + bias + sigmoid, single pass.
// logit = rs*(sum(x*gw) - mu*sum(gw)) + sum(beta*W) + bias,  gw = gamma*W
//
// A/B vs R5: identical kernel but PLAIN loads for x (no nontemporal).
// Isolates whether R5's 42.7us regression was the nt cache-bypass path
// (expected) or the gw-in-registers occupancy cost (alternative).
// Barrier-free / LDS-free: each 16-lane group holds the ENTIRE gw[768] in
// registers (16 lanes x 12 float4; idx = sl*4+k*64 covers 0..767). Per-wave
// prologue computes gw + both scalar consts with intra-group shuffles only.
__global__ __launch_bounds__(256) void head_kernel(
    const float* __restrict__ x, const float* __restrict__ gamma,
    const float* __restrict__ beta, const float* __restrict__ W,
    const float* __restrict__ bias, float* __restrict__ out) {
    const int t    = threadIdx.x;
    const int lane = t & 63;
    const int wv   = t >> 6;
    const int sl   = lane & 15;   // sub-lane within the row's 16-lane group
    const int grp  = lane >> 4;   // which of the wave's 4 rows

    // ---- prologue: gw into registers, consts via intra-group reduce ----
    floatx4 gw[12];
    float sgw = 0.f, sbw = 0.f;
#pragma unroll
    for (int k = 0; k < 12; ++k) {
        const int idx = sl * 4 + k * 64;
        floatx4 w  = *reinterpret_cast<const floatx4*>(W + idx);
        floatx4 g  = *reinterpret_cast<const floatx4*>(gamma + idx);
        floatx4 bt = *reinterpret_cast<const floatx4*>(beta + idx);
        floatx4 gv = g * w;
        gw[k] = gv;
        sgw += gv.x + gv.y + gv.z + gv.w;
        sbw += bt.x * w.x + bt.y * w.y + bt.z * w.z + bt.w * w.w;
    }
#pragma unroll
    for (int m = 8; m; m >>= 1) {
        sgw += __shfl_xor(sgw, m);
        sbw += __shfl_xor(sbw, m);
    }
    const float c0 = sgw;
    const float c1 = sbw + bias[0];
    const float inv_e = 1.0f / 768.0f;

    // ---- main: 16 rows/block = 4 waves x 4 rows; 16 lanes per row ----
    const int row = blockIdx.x * 16 + wv * 4 + grp;   // 0 .. 65535
    const int b   = row >> 8;
    const int n   = row & 255;
    const float* __restrict__ xr = x + (size_t)(b * 257 + n + 1) * 768;

    float s1 = 0.f, s2 = 0.f, s3 = 0.f;
#pragma unroll
    for (int k = 0; k < 12; ++k) {
        const int idx = sl * 4 + k * 64;  // 16 lanes x float4 = 256B/group
        floatx4 v = *reinterpret_cast<const floatx4*>(xr + idx);
        s1 += v.x + v.y + v.z + v.w;
        s2 += v.x * v.x + v.y * v.y + v.z * v.z + v.w * v.w;
        s3 += v.x * gw[k].x + v.y * gw[k].y + v.z * gw[k].z + v.w * gw[k].w;
    }
    // butterfly over the 16-lane group: reduces the wave's 4 rows at once
#pragma unroll
    for (int m = 8; m; m >>= 1) {
        s1 += __shfl_xor(s1, m);
        s2 += __shfl_xor(s2, m);
        s3 += __shfl_xor(s3, m);
    }
    if (sl == 0) {
        float mu  = s1 * inv_e;
        float var = s2 * inv_e - mu * mu;
        float rs  = rsqrtf(var + EPS);
        float logit = rs * (s3 - mu * c0) + c1;
        out[row] = 1.0f / (1.0f + __expf(-logit));  // lanes 0/16/32/48 -> 16B
    }
}

extern "C" void kernel_launch(void* const* d_in, const int* in_sizes, int n_in,
                              void* d_out, int out_size, void* d_ws, size_t ws_size,
                              hipStream_t stream) {
    const float* x     = (const float*)d_in[0];   // (256, 257, 768)
    const float* gamma = (const float*)d_in[1];   // (768,)
    const float* beta  = (const float*)d_in[2];   // (768,)
    const float* W     = (const float*)d_in[3];   // (1, 768)
    const float* bias  = (const float*)d_in[4];   // (1,)
    float* out = (float*)d_out;                   // 65536 floats

    const int rows = 256 * 256;                   // 16 rows per block
    head_kernel<<<rows / 16, 256, 0, stream>>>(x, gamma, beta, W, bias, out);
}

// Round 7
// 35.817 us; speedup vs baseline: 1.1931x; 1.0141x over previous
//
#include <hip/hip_runtime.h>
#include <hip/hip_bf16.h>

#define EPS 1e-5f

// Fully fused: slice + LayerNorm + dot(W) + bias + sigmoid, single pass.
// logit = rs*(sum(x*gw) - mu*sum(gw)) + sum(beta*W) + bias,  gw = gamma*W
//
// BEST KNOWN (R2 structure, 35.16us = ~97% of the 6.29 TB/s copy ceiling
// after ~2us dispatch overhead). A/B history: NT loads -21% (R5/R6: cache
// bypass kills read BW); reg-held gw -3% vs LDS (R6: +48 VGPR not free);
// 2048-block persistent grid -2% (R3); prologue/barriers measured <1%.
//
// Per block: prologue computes gw[768] + 2 consts into LDS.
// Main: 4 waves/block, each wave processes 4 rows with 16 lanes/row, so one
// butterfly step reduces 4 rows at once (3 shfl/row).
__global__ __launch_bounds__(256) void head_kernel(
    const float* __restrict__ x, const float* __restrict__ gamma,
    const float* __restrict__ beta, const float* __restrict__ W,
    const float* __restrict__ bias, float* __restrict__ out) {
    __shared__ float s_gw[768];
    __shared__ float s_red[8];
    __shared__ float s_c[2];

    const int t = threadIdx.x;

    // ---- per-block prologue: gw into LDS + consts (gamma/beta/W are L2-hot) ----
    {
        float sgw = 0.f, sbw = 0.f;
#pragma unroll
        for (int i = t; i < 768; i += 256) {
            float w  = W[i];
            float gv = gamma[i] * w;
            s_gw[i] = gv;
            sgw += gv;
            sbw += beta[i] * w;
        }
#pragma unroll
        for (int m = 32; m; m >>= 1) {
            sgw += __shfl_xor(sgw, m);
            sbw += __shfl_xor(sbw, m);
        }
        const int wv = t >> 6;
        if ((t & 63) == 0) { s_red[wv * 2] = sgw; s_red[wv * 2 + 1] = sbw; }
        __syncthreads();
        if (t == 0) {
            s_c[0] = s_red[0] + s_red[2] + s_red[4] + s_red[6];
            s_c[1] = s_red[1] + s_red[3] + s_red[5] + s_red[7] + bias[0];
        }
        __syncthreads();
    }

    // ---- main: 16 rows/block = 4 waves x 4 rows; 16 lanes per row ----
    const int lane = t & 63;
    const int wv   = t >> 6;
    const int sl   = lane & 15;   // sub-lane within the row's 16-lane group
    const int grp  = lane >> 4;   // which of the wave's 4 rows
    const int row  = blockIdx.x * 16 + wv * 4 + grp;   // 0 .. 65535
    const int b    = row >> 8;
    const int n    = row & 255;
    const float* __restrict__ xr = x + (size_t)(b * 257 + n + 1) * 768;

    float s1 = 0.f, s2 = 0.f, s3 = 0.f;
#pragma unroll
    for (int k = 0; k < 12; ++k) {
        const int idx = sl * 4 + k * 64;   // 16 lanes x float4 = contiguous 256B/group
        float4 v = *reinterpret_cast<const float4*>(xr + idx);
        float4 w = *reinterpret_cast<const float4*>(s_gw + idx);
        s1 += v.x + v.y + v.z + v.w;
        s2 += v.x * v.x + v.y * v.y + v.z * v.z + v.w * v.w;
        s3 += v.x * w.x + v.y * w.y + v.z * w.z + v.w * w.w;
    }
    // butterfly over the 16-lane group: reduces all 4 rows of the wave at once
#pragma unroll
    for (int m = 8; m; m >>= 1) {
        s1 += __shfl_xor(s1, m);
        s2 += __shfl_xor(s2, m);
        s3 += __shfl_xor(s3, m);
    }
    if (sl == 0) {
        const float inv_e = 1.0f / 768.0f;
        float mu  = s1 * inv_e;
        float var = s2 * inv_e - mu * mu;
        float rs  = rsqrtf(var + EPS);
        float logit = rs * (s3 - mu * s_c[0]) + s_c[1];
        out[row] = 1.0f / (1.0f + __expf(-logit));   // lanes 0/16/32/48 -> 16B store
    }
}

extern "C" void kernel_launch(void* const* d_in, const int* in_sizes, int n_in,
                              void* d_out, int out_size, void* d_ws, size_t ws_size,
                              hipStream_t stream) {
    const float* x     = (const float*)d_in[0];   // (256, 257, 768)
    const float* gamma = (const float*)d_in[1];   // (768,)
    const float* beta  = (const float*)d_in[2];   // (768,)
    const float* W     = (const float*)d_in[3];   // (1, 768)
    const float* bias  = (const float*)d_in[4];   // (1,)
    float* out = (float*)d_out;                   // 65536 floats

    const int rows = 256 * 256;                   // 16 rows per block
    head_kernel<<<rows / 16, 256, 0, stream>>>(x, gamma, beta, W, bias, out);
}